// Round 6
// baseline (61.950 us; speedup 1.0000x reference)
//
#include <hip/hip_runtime.h>
#include <math.h>

#define EPS 1e-6f

typedef float vfloat4 __attribute__((ext_vector_type(4)));

// One point per thread (round-1 structure — fastest so far at 49.96us).
// Pure streaming kernel, zero reuse, 302MB footprint > 256MiB L3:
// use non-temporal loads/stores (nt flag) to skip LLC allocation.
__global__ __launch_bounds__(256) void deform_nt(
    const float* __restrict__ pos,   // (N,3)
    const float* __restrict__ net,   // (N,12)
    float* __restrict__ out,         // (N,3)
    int n)
{
    int i = blockIdx.x * blockDim.x + threadIdx.x;
    if (i >= n) return;

    // network_output row: w(3), v(3), pivot(3), translation(3) — 48B, float4-aligned
    const vfloat4* net4 = reinterpret_cast<const vfloat4*>(net);
    vfloat4 a = __builtin_nontemporal_load(&net4[i * 3 + 0]);  // wx wy wz vx
    vfloat4 b = __builtin_nontemporal_load(&net4[i * 3 + 1]);  // vy vz px py
    vfloat4 c = __builtin_nontemporal_load(&net4[i * 3 + 2]);  // pz tx ty tz

    float wx = a.x, wy = a.y, wz = a.z;
    float vx = a.w, vy = b.x, vz = b.y;
    float px = b.z, py = b.w, pz = c.x;
    float tx = c.y, ty = c.z, tz = c.w;

    float x0 = __builtin_nontemporal_load(&pos[i * 3 + 0]);
    float x1 = __builtin_nontemporal_load(&pos[i * 3 + 1]);
    float x2 = __builtin_nontemporal_load(&pos[i * 3 + 2]);

    float theta = sqrtf(wx * wx + wy * wy + wz * wz) + EPS;
    float inv = 1.0f / theta;
    wx *= inv; wy *= inv; wz *= inv;
    vx *= inv; vy *= inv; vz *= inv;

    float s, co;
    sincosf(theta, &s, &co);
    float c1 = 1.0f - co;     // 1 - cos(theta)
    float c2 = theta - s;     // theta - sin(theta)

    // p = theta*v + c1*(w x v) + c2*(w x (w x v))
    float cvx = wy * vz - wz * vy;
    float cvy = wz * vx - wx * vz;
    float cvz = wx * vy - wy * vx;
    float ccvx = wy * cvz - wz * cvy;
    float ccvy = wz * cvx - wx * cvz;
    float ccvz = wx * cvy - wy * cvx;
    float p0 = theta * vx + c1 * cvx + c2 * ccvx;
    float p1 = theta * vy + c1 * cvy + c2 * ccvy;
    float p2 = theta * vz + c1 * cvz + c2 * ccvz;

    // r = x + pivot
    float r0 = x0 + px, r1 = x1 + py, r2 = x2 + pz;

    // offset = s*(w x r) + c1*(w x (w x r)) + p + t
    float crx = wy * r2 - wz * r1;
    float cry = wz * r0 - wx * r2;
    float crz = wx * r1 - wy * r0;
    float ccrx = wy * crz - wz * cry;
    float ccry = wz * crx - wx * crz;
    float ccrz = wx * cry - wy * crx;

    __builtin_nontemporal_store(s * crx + c1 * ccrx + p0 + tx, &out[i * 3 + 0]);
    __builtin_nontemporal_store(s * cry + c1 * ccry + p1 + ty, &out[i * 3 + 1]);
    __builtin_nontemporal_store(s * crz + c1 * ccrz + p2 + tz, &out[i * 3 + 2]);
}

extern "C" void kernel_launch(void* const* d_in, const int* in_sizes, int n_in,
                              void* d_out, int out_size, void* d_ws, size_t ws_size,
                              hipStream_t stream) {
    const float* pos = (const float*)d_in[0];   // undeformed_positions (N,3)
    const float* net = (const float*)d_in[1];   // network_output (N,12)
    float* out = (float*)d_out;                 // offsets (N,3)
    int n = in_sizes[0] / 3;                    // N points

    int block = 256;
    int grid = (n + block - 1) / block;
    deform_nt<<<grid, block, 0, stream>>>(pos, net, out, n);
}

// Round 7
// 47.062 us; speedup vs baseline: 1.3164x; 1.3164x over previous
//
#include <hip/hip_runtime.h>
#include <math.h>

#define EPS 1e-6f

// Round-1 structure (fastest: 49.96us), plus non-temporal STORES only.
// Loads stay on the normal cached path (R6 showed NT loads regress 24% —
// the 12B-stride scalar streams rely on L1/L2 line reuse).
// Stores are write-once-never-read: NT skips LLC allocation, freeing
// cache capacity/eviction BW for the 252MB read side.
__global__ __launch_bounds__(256) void deform_ntst(
    const float* __restrict__ pos,   // (N,3)
    const float* __restrict__ net,   // (N,12)
    float* __restrict__ out,         // (N,3)
    int n)
{
    int i = blockIdx.x * blockDim.x + threadIdx.x;
    if (i >= n) return;

    // network_output row: w(3), v(3), pivot(3), translation(3) — 48B, float4-aligned
    const float4* net4 = reinterpret_cast<const float4*>(net);
    float4 a = net4[i * 3 + 0];  // wx wy wz vx
    float4 b = net4[i * 3 + 1];  // vy vz px py
    float4 c = net4[i * 3 + 2];  // pz tx ty tz

    float wx = a.x, wy = a.y, wz = a.z;
    float vx = a.w, vy = b.x, vz = b.y;
    float px = b.z, py = b.w, pz = c.x;
    float tx = c.y, ty = c.z, tz = c.w;

    float x0 = pos[i * 3 + 0];
    float x1 = pos[i * 3 + 1];
    float x2 = pos[i * 3 + 2];

    float theta = sqrtf(wx * wx + wy * wy + wz * wz) + EPS;
    float inv = 1.0f / theta;
    wx *= inv; wy *= inv; wz *= inv;
    vx *= inv; vy *= inv; vz *= inv;

    float s, co;
    sincosf(theta, &s, &co);
    float c1 = 1.0f - co;     // 1 - cos(theta)
    float c2 = theta - s;     // theta - sin(theta)

    // p = theta*v + c1*(w x v) + c2*(w x (w x v))
    float cvx = wy * vz - wz * vy;
    float cvy = wz * vx - wx * vz;
    float cvz = wx * vy - wy * vx;
    float ccvx = wy * cvz - wz * cvy;
    float ccvy = wz * cvx - wx * cvz;
    float ccvz = wx * cvy - wy * cvx;
    float p0 = theta * vx + c1 * cvx + c2 * ccvx;
    float p1 = theta * vy + c1 * cvy + c2 * ccvy;
    float p2 = theta * vz + c1 * cvz + c2 * ccvz;

    // r = x + pivot
    float r0 = x0 + px, r1 = x1 + py, r2 = x2 + pz;

    // offset = s*(w x r) + c1*(w x (w x r)) + p + t
    float crx = wy * r2 - wz * r1;
    float cry = wz * r0 - wx * r2;
    float crz = wx * r1 - wy * r0;
    float ccrx = wy * crz - wz * cry;
    float ccry = wz * crx - wx * crz;
    float ccrz = wx * cry - wy * crx;

    __builtin_nontemporal_store(s * crx + c1 * ccrx + p0 + tx, &out[i * 3 + 0]);
    __builtin_nontemporal_store(s * cry + c1 * ccry + p1 + ty, &out[i * 3 + 1]);
    __builtin_nontemporal_store(s * crz + c1 * ccrz + p2 + tz, &out[i * 3 + 2]);
}

extern "C" void kernel_launch(void* const* d_in, const int* in_sizes, int n_in,
                              void* d_out, int out_size, void* d_ws, size_t ws_size,
                              hipStream_t stream) {
    const float* pos = (const float*)d_in[0];   // undeformed_positions (N,3)
    const float* net = (const float*)d_in[1];   // network_output (N,12)
    float* out = (float*)d_out;                 // offsets (N,3)
    int n = in_sizes[0] / 3;                    // N points

    int block = 256;
    int grid = (n + block - 1) / block;
    deform_ntst<<<grid, block, 0, stream>>>(pos, net, out, n);
}